// Round 11
// baseline (1393.291 us; speedup 1.0000x reference)
//
#include <hip/hip_runtime.h>
#include <hip/hip_bf16.h>
#include <stdint.h>

#define H 3072
#define EXPERTS 4
#define MTOK 8192          // B*T
#define LN_EPS 1e-5f
#define FLAG_CAP 1024
#define TAU 0.03f          // layer-2 router logit gap threshold for refinement
#define NT_MAX 70          // max M-tiles after per-bucket 128-padding
#define KSPLIT 2           // refine split-K factor

#define BM 128
#define BN 128
#define BK 32              // refine kernel K-step
#define BKG 64             // main gemm K-step
#define RBM 64             // refine M-tile (finer split for latency hiding)

typedef __bf16 bf16;
typedef __bf16 bf16x8 __attribute__((ext_vector_type(8)));
typedef __bf16 bf16x4 __attribute__((ext_vector_type(4)));
typedef float  f32x4  __attribute__((ext_vector_type(4)));

typedef const __attribute__((address_space(1))) unsigned char* gas1p;
typedef __attribute__((address_space(3))) unsigned char* las3p;

__device__ __forceinline__ void gload_lds16(const void* g, void* l) {
    __builtin_amdgcn_global_load_lds((gas1p)g, (las3p)l, 16, 0, 0);
}

__device__ __forceinline__ int pair_a(int b) { return b < 3 ? 0 : (b < 5 ? 1 : 2); }
__device__ __forceinline__ int pair_b(int b) { return b < 3 ? b + 1 : (b < 5 ? b - 1 : 3); }

// ---------------------------------------------------------------------------
// Kernel 1: We fp32 [E][K][N] -> Wt_hi/Wt_lo bf16 [E][N][K] (split transpose)
// Write side vectorized to bf16x8 (16 B/lane).
// ---------------------------------------------------------------------------
template <int WLO>
__global__ __launch_bounds__(256) void we_transpose(const float* __restrict__ We,
                                                    bf16* __restrict__ Wt_hi,
                                                    bf16* __restrict__ Wt_lo) {
    __shared__ float tile[64][65];
    const int e  = blockIdx.z;
    const int k0 = blockIdx.y * 64;
    const int n0 = blockIdx.x * 64;
    const int tid = threadIdx.x;

    const float* src = We + ((size_t)e * H + k0) * H + n0;
    const int kl = tid >> 4;
    const int nl = (tid & 15) * 4;
#pragma unroll
    for (int it = 0; it < 4; ++it) {
        float4 v = *(const float4*)(src + (size_t)(kl + it * 16) * H + nl);
        tile[kl + it * 16][nl + 0] = v.x;
        tile[kl + it * 16][nl + 1] = v.y;
        tile[kl + it * 16][nl + 2] = v.z;
        tile[kl + it * 16][nl + 3] = v.w;
    }
    __syncthreads();
    const size_t dbase = ((size_t)e * H + n0) * H + k0;
    const int nl2 = tid >> 3;          // 0..31 (n-row)
    const int kl2 = (tid & 7) * 8;     // 0..56 (k-chunk)
#pragma unroll
    for (int it = 0; it < 2; ++it) {
        const int row = nl2 + it * 32;
        bf16x8 oh, ol;
#pragma unroll
        for (int j = 0; j < 8; ++j) {
            float v = tile[kl2 + j][row];
            bf16 hi = (bf16)v;
            oh[j] = hi;
            ol[j] = (bf16)(v - (float)hi);
        }
        const size_t doff = dbase + (size_t)row * H + kl2;
        *(bf16x8*)(Wt_hi + doff) = oh;
        if (WLO) *(bf16x8*)(Wt_lo + doff) = ol;
    }
}

// ---------------------------------------------------------------------------
// Kernel 2: LayerNorm (fp32, two-pass var) + router per token.
// (unchanged from r10 — preserves proven summation order)
// ---------------------------------------------------------------------------
template <int MODE>
__global__ __launch_bounds__(256) void ln_router_k(const float* __restrict__ xin,
                                                   const float* __restrict__ gamma,
                                                   const float* __restrict__ beta,
                                                   const float* __restrict__ Wr,   // [H][4]
                                                   const float* __restrict__ br,   // [4]
                                                   bf16* __restrict__ z,
                                                   float* __restrict__ wout,
                                                   int* __restrict__ bkt,
                                                   int* __restrict__ bcount,
                                                   int* __restrict__ flags) {
    __shared__ float red[4][4];
    __shared__ float bc[2];

    const int t    = blockIdx.x;
    const int tid  = threadIdx.x;
    const int wid  = tid >> 6;
    const int lane = tid & 63;
    const float* xrow = xin + (size_t)t * H;

    float4 xv[3];
    float s = 0.f;
#pragma unroll
    for (int c = 0; c < 3; ++c) {
        xv[c] = *(const float4*)(xrow + (c * 256 + tid) * 4);
        s += xv[c].x + xv[c].y + xv[c].z + xv[c].w;
    }
#pragma unroll
    for (int off = 32; off; off >>= 1) s += __shfl_down(s, off);
    if (lane == 0) red[wid][0] = s;
    __syncthreads();
    if (tid == 0) bc[0] = (red[0][0] + red[1][0] + red[2][0] + red[3][0]) * (1.f / (float)H);
    __syncthreads();
    const float mu = bc[0];

    float d = 0.f;
#pragma unroll
    for (int c = 0; c < 3; ++c) {
        float dx;
        dx = xv[c].x - mu; d += dx * dx;
        dx = xv[c].y - mu; d += dx * dx;
        dx = xv[c].z - mu; d += dx * dx;
        dx = xv[c].w - mu; d += dx * dx;
    }
#pragma unroll
    for (int off = 32; off; off >>= 1) d += __shfl_down(d, off);
    if (lane == 0) red[wid][1] = d;
    __syncthreads();
    if (tid == 0) {
        float var = (red[0][1] + red[1][1] + red[2][1] + red[3][1]) * (1.f / (float)H);
        bc[1] = 1.f / sqrtf(var + LN_EPS);
    }
    __syncthreads();
    const float rs = bc[1];

    float l0 = 0.f, l1 = 0.f, l2 = 0.f, l3 = 0.f;
    bf16* zrow = z + (size_t)t * H;
#pragma unroll
    for (int c = 0; c < 3; ++c) {
        const int i0 = (c * 256 + tid) * 4;
        float4 gv = *(const float4*)(gamma + i0);
        float4 bv = *(const float4*)(beta + i0);
        float zz[4];
        zz[0] = (xv[c].x - mu) * rs * gv.x + bv.x;
        zz[1] = (xv[c].y - mu) * rs * gv.y + bv.y;
        zz[2] = (xv[c].z - mu) * rs * gv.z + bv.z;
        zz[3] = (xv[c].w - mu) * rs * gv.w + bv.w;
        if (MODE == 0) {
            bf16x4 zb = { (bf16)zz[0], (bf16)zz[1], (bf16)zz[2], (bf16)zz[3] };
            *(bf16x4*)(zrow + i0) = zb;
        }
#pragma unroll
        for (int j = 0; j < 4; ++j) {
            float4 wr = *(const float4*)(Wr + (size_t)(i0 + j) * 4);
            l0 += zz[j] * wr.x; l1 += zz[j] * wr.y;
            l2 += zz[j] * wr.z; l3 += zz[j] * wr.w;
        }
    }
    __syncthreads();
#pragma unroll
    for (int off = 32; off; off >>= 1) {
        l0 += __shfl_down(l0, off);
        l1 += __shfl_down(l1, off);
        l2 += __shfl_down(l2, off);
        l3 += __shfl_down(l3, off);
    }
    if (lane == 0) { red[wid][0] = l0; red[wid][1] = l1; red[wid][2] = l2; red[wid][3] = l3; }
    __syncthreads();
    if (tid == 0) {
        float lf[4];
#pragma unroll
        for (int e = 0; e < 4; ++e)
            lf[e] = red[0][e] + red[1][e] + red[2][e] + red[3][e] + br[e];
        if (MODE == 0) {
            float mx = fmaxf(fmaxf(lf[0], lf[1]), fmaxf(lf[2], lf[3]));
            float p[4]; float ps = 0.f;
#pragma unroll
            for (int e = 0; e < 4; ++e) { p[e] = expf(lf[e] - mx); ps += p[e]; }
#pragma unroll
            for (int e = 0; e < 4; ++e) p[e] /= ps;
            int i1 = 0; float v1 = p[0];
#pragma unroll
            for (int e = 1; e < 4; ++e) if (p[e] > v1) { v1 = p[e]; i1 = e; }
            int i2 = -1; float v2 = -1.f;
#pragma unroll
            for (int e = 0; e < 4; ++e) if (e != i1 && p[e] > v2) { v2 = p[e]; i2 = e; }
            const float den = fmaxf(v1 + v2, 1e-8f);
            float w4[4] = {0.f, 0.f, 0.f, 0.f};
            w4[i1] = v1 / den;
            w4[i2] = v2 / den;
            *(float4*)(wout + (size_t)t * 4) = make_float4(w4[0], w4[1], w4[2], w4[3]);
            const int lo = min(i1, i2), hi = max(i1, i2);
            const int b = (lo == 0) ? hi - 1 : (lo == 1 ? hi + 1 : 5);
            bkt[t] = b;
            atomicAdd(&bcount[b], 1);
        } else {
            float a = lf[0], b = lf[1], c = lf[2], dd = lf[3], t1;
#define SW_(p,q) if (p < q) { t1 = p; p = q; q = t1; }
            SW_(a, b) SW_(c, dd) SW_(a, c) SW_(b, dd) SW_(b, c)
#undef SW_
            if (b - c < TAU) {
                int idx = atomicAdd(flags, 1);
                if (idx < FLAG_CAP) flags[1 + idx] = t;
            }
        }
    }
}

__global__ void zero_flags(int* flags) { if (threadIdx.x == 0) flags[0] = 0; }
__global__ void zero12(int* bcount) { if (threadIdx.x < 12) bcount[threadIdx.x] = 0; }

// ---------------------------------------------------------------------------
// bucket_scan: 1 block. Padded-prefix offsets, per-tile bucket/end tables.
// ---------------------------------------------------------------------------
__global__ __launch_bounds__(256) void bucket_scan(const int* __restrict__ bcount,
                                                   int* __restrict__ off_g,
                                                   int* __restrict__ tile_bkt,
                                                   int* __restrict__ tile_end,
                                                   int* __restrict__ tokslot) {
    for (int i = threadIdx.x; i < NT_MAX * BM; i += 256) tokslot[i] = 0;
    if (threadIdx.x == 0) {
        int off = 0, tile = 0;
        for (int b = 0; b < 6; ++b) {
            off_g[b] = off;
            const int c = bcount[b];
            const int ntb = (c + BM - 1) / BM;
            for (int k = 0; k < ntb; ++k) { tile_bkt[tile] = b; tile_end[tile] = off + c; ++tile; }
            off += ntb * BM;
        }
        for (; tile < NT_MAX; ++tile) { tile_bkt[tile] = -1; tile_end[tile] = 0; }
    }
}

// ---------------------------------------------------------------------------
// scatter_scale (fused slot assignment): thread 0 claims the slot, then all
// threads write zA[slot] = w_a*z[t], zB[slot] = w_b*z[t]. Output values are
// slot-permutation invariant -> deterministic results.
// ---------------------------------------------------------------------------
__global__ __launch_bounds__(384) void scatter_scale(const bf16* __restrict__ z,
                                                     const float* __restrict__ wb,
                                                     const int* __restrict__ bkt,
                                                     const int* __restrict__ off_g,
                                                     int* __restrict__ cursor,
                                                     int* __restrict__ tokslot,
                                                     bf16* __restrict__ zA,
                                                     bf16* __restrict__ zB) {
    __shared__ int sslot;
    const int t = blockIdx.x;
    const int b = bkt[t];
    if (threadIdx.x == 0) {
        const int s = off_g[b] + atomicAdd(&cursor[b], 1);
        sslot = s;
        tokslot[s] = t;
    }
    const float wa = wb[(size_t)t * 4 + pair_a(b)];
    const float wv = wb[(size_t)t * 4 + pair_b(b)];
    const int i0 = threadIdx.x * 8;
    const bf16x8 v = *(const bf16x8*)(z + (size_t)t * H + i0);
    bf16x8 ra, rb;
#pragma unroll
    for (int j = 0; j < 8; ++j) {
        const float f = (float)v[j];
        ra[j] = (bf16)(f * wa);
        rb[j] = (bf16)(f * wv);
    }
    __syncthreads();
    const size_t slot = (size_t)sslot;
    *(bf16x8*)(zA + slot * H + i0) = ra;
    *(bf16x8*)(zB + slot * H + i0) = rb;
}

// ---------------------------------------------------------------------------
// zfill: fp32 layer-1 LN for flagged tokens -> compact hi/lo bf16 rows + w1.
// ---------------------------------------------------------------------------
__global__ __launch_bounds__(256) void zfill(const float* __restrict__ x,
                                             const float* __restrict__ gamma,
                                             const float* __restrict__ beta,
                                             const int* __restrict__ flags,
                                             const float* __restrict__ wb,
                                             bf16* __restrict__ zc_hi,
                                             bf16* __restrict__ zc_lo,
                                             float* __restrict__ wfo) {
    __shared__ float red[4][2];
    __shared__ float bc[2];
    const int i = blockIdx.x;
    int count = flags[0]; if (count > FLAG_CAP) count = FLAG_CAP;
    if (i >= count) return;
    const int t = flags[1 + i];
    const int tid = threadIdx.x, wid = tid >> 6, lane = tid & 63;
    const float* xrow = x + (size_t)t * H;

    float4 xv[3]; float s = 0.f;
#pragma unroll
    for (int c = 0; c < 3; ++c) {
        xv[c] = *(const float4*)(xrow + (c * 256 + tid) * 4);
        s += xv[c].x + xv[c].y + xv[c].z + xv[c].w;
    }
#pragma unroll
    for (int off = 32; off; off >>= 1) s += __shfl_down(s, off);
    if (lane == 0) red[wid][0] = s;
    __syncthreads();
    if (tid == 0) bc[0] = (red[0][0] + red[1][0] + red[2][0] + red[3][0]) * (1.f / (float)H);
    __syncthreads();
    const float mu = bc[0];
    float d = 0.f;
#pragma unroll
    for (int c = 0; c < 3; ++c) {
        float dx;
        dx = xv[c].x - mu; d += dx * dx;
        dx = xv[c].y - mu; d += dx * dx;
        dx = xv[c].z - mu; d += dx * dx;
        dx = xv[c].w - mu; d += dx * dx;
    }
#pragma unroll
    for (int off = 32; off; off >>= 1) d += __shfl_down(d, off);
    if (lane == 0) red[wid][1] = d;
    __syncthreads();
    if (tid == 0) bc[1] = 1.f / sqrtf((red[0][1] + red[1][1] + red[2][1] + red[3][1]) * (1.f / (float)H) + LN_EPS);
    __syncthreads();
    const float rs = bc[1];

    bf16* zh = zc_hi + (size_t)i * H;
    bf16* zl = zc_lo + (size_t)i * H;
#pragma unroll
    for (int c = 0; c < 3; ++c) {
        const int i0 = (c * 256 + tid) * 4;
        float4 gv = *(const float4*)(gamma + i0);
        float4 bv = *(const float4*)(beta + i0);
        float vv[4];
        vv[0] = (xv[c].x - mu) * rs * gv.x + bv.x;
        vv[1] = (xv[c].y - mu) * rs * gv.y + bv.y;
        vv[2] = (xv[c].z - mu) * rs * gv.z + bv.z;
        vv[3] = (xv[c].w - mu) * rs * gv.w + bv.w;
        bf16x4 oh, ol;
#pragma unroll
        for (int j = 0; j < 4; ++j) {
            bf16 hi = (bf16)vv[j];
            oh[j] = hi;
            ol[j] = (bf16)(vv[j] - (float)hi);
        }
        *(bf16x4*)(zh + i0) = oh;
        *(bf16x4*)(zl + i0) = ol;
    }
    if (tid == 0) *(float4*)(wfo + (size_t)i * 4) = *(const float4*)(wb + (size_t)t * 4);
}

// ---------------------------------------------------------------------------
// refine_mfma: RBM=64 M-tiles, split-K per-expert partials, hi/lo split MFMA,
// double-buffered staging, swizzled LDS. grid (H/BN, FLAG_CAP/RBM, E*KSPLIT).
// ---------------------------------------------------------------------------
__global__ __launch_bounds__(256) void refine_mfma(const bf16* __restrict__ zc_hi,
                                                   const bf16* __restrict__ zc_lo,
                                                   const bf16* __restrict__ Wt_hi,
                                                   const bf16* __restrict__ Wt_lo,
                                                   const float* __restrict__ wf,
                                                   const int* __restrict__ flags,
                                                   float* __restrict__ partial) {
    int count = flags[0]; if (count > FLAG_CAP) count = FLAG_CAP;
    const int tileM = blockIdx.y * RBM;
    if (tileM >= count) return;
    const int ez = blockIdx.z;          // e*KSPLIT + ks
    const int e  = ez >> 1;
    const int ks = ez & 1;
    const int kbeg = ks * (H / KSPLIT / BK);
    const int kend = kbeg + H / KSPLIT / BK;

    __shared__ __align__(16) bf16 Ah[2][RBM * BK];
    __shared__ __align__(16) bf16 Al[2][RBM * BK];
    __shared__ __align__(16) bf16 Bh[2][BN * BK];
    __shared__ __align__(16) bf16 Bl[2][BN * BK];
    __shared__ float wlds[RBM];

    const int tid  = threadIdx.x;
    const int wid  = tid >> 6;
    const int lane = tid & 63;
    const int wm   = wid >> 1;          // 0..1 over 32-row halves
    const int wn   = wid & 1;           // 0..1 over 64-col halves
    const int tileN = blockIdx.x * BN;

    if (tid < RBM) wlds[tid] = wf[(size_t)(tileM + tid) * 4 + e];

    const int srow   = lane >> 2;
    const int schunk = (((lane & 3) ^ ((lane >> 3) & 3)) * 8);
    const int lrow   = lane & 15;
    const int rchunk = (((lane >> 4) ^ ((lane >> 1) & 3)) * 8);
    const int r0   = wm * 32 + (lane >> 4) * 4;
    const int c0   = tileN + wn * 64 + (lane & 15);

    const bf16* Ahb = zc_hi;
    const bf16* Alb = zc_lo;
    const bf16* Bhb = Wt_hi + ((size_t)e * H + tileN) * H;
    const bf16* Blb = Wt_lo + ((size_t)e * H + tileN) * H;

#define RSTAGE(buf, kk0)                                                              \
    {                                                                                 \
        const int rrA = wid * 16;                                                     \
        gload_lds16(Ahb + (size_t)(tileM + rrA + srow) * H + (kk0) + schunk,          \
                    &Ah[buf][(size_t)rrA * BK]);                                      \
        gload_lds16(Alb + (size_t)(tileM + rrA + srow) * H + (kk0) + schunk,          \
                    &Al[buf][(size_t)rrA * BK]);                                      \
        _Pragma("unroll")                                                             \
        for (int i_ = 0; i_ < 2; ++i_) {                                              \
            const int rr_ = wid * 32 + i_ * 16;                                       \
            gload_lds16(Bhb + (size_t)(rr_ + srow) * H + (kk0) + schunk,              \
                        &Bh[buf][(size_t)rr_ * BK]);                                  \
            gload_lds16(Blb + (size_t)(rr_ + srow) * H + (kk0) + schunk,              \
                        &Bl[buf][(size_t)rr_ * BK]);                                  \
        }                                                                             \
    }

    f32x4 acc[2][4];
#pragma unroll
    for (int m = 0; m < 2; ++m)
#pragma unroll
        for (int n = 0; n < 4; ++n)
            acc[m][n] = (f32x4){0.f, 0.f, 0.f, 0.f};

    RSTAGE(0, kbeg * BK)
    __syncthreads();

    int cur = 0;
    for (int kk = kbeg; kk < kend; ++kk) {
        if (kk + 1 < kend) { RSTAGE(cur ^ 1, (kk + 1) * BK) }

        bf16x8 ah[2], al[2], bh[4], bl[4];
#pragma unroll
        for (int m = 0; m < 2; ++m) {
            ah[m] = *(const bf16x8*)&Ah[cur][(wm * 32 + m * 16 + lrow) * BK + rchunk];
            al[m] = *(const bf16x8*)&Al[cur][(wm * 32 + m * 16 + lrow) * BK + rchunk];
        }
#pragma unroll
        for (int n = 0; n < 4; ++n) {
            bh[n] = *(const bf16x8*)&Bh[cur][(wn * 64 + n * 16 + lrow) * BK + rchunk];
            bl[n] = *(const bf16x8*)&Bl[cur][(wn * 64 + n * 16 + lrow) * BK + rchunk];
        }
#pragma unroll
        for (int m = 0; m < 2; ++m)
#pragma unroll
            for (int n = 0; n < 4; ++n) {
                acc[m][n] = __builtin_amdgcn_mfma_f32_16x16x32_bf16(al[m], bh[n], acc[m][n], 0, 0, 0);
                acc[m][n] = __builtin_amdgcn_mfma_f32_16x16x32_bf16(ah[m], bl[n], acc[m][n], 0, 0, 0);
                acc[m][n] = __builtin_amdgcn_mfma_f32_16x16x32_bf16(ah[m], bh[n], acc[m][n], 0, 0, 0);
            }
        __syncthreads();
        cur ^= 1;
    }
#undef RSTAGE

#pragma unroll
    for (int m = 0; m < 2; ++m) {
#pragma unroll
        for (int r = 0; r < 4; ++r) {
            const int tl = r0 + m * 16 + r;
            const int g = tileM + tl;
            if (g < count) {
                const float w = wlds[tl];
                float* prow = partial + ((size_t)ez * FLAG_CAP + g) * H;
#pragma unroll
                for (int n = 0; n < 4; ++n)
                    prow[c0 + n * 16] = w * acc[m][n][r];
            }
        }
    }
}

// ---------------------------------------------------------------------------
// refine_combine: out[t] = x[t] + sum_ez partial[ez][i] + sum_e w_e*be_e
// ---------------------------------------------------------------------------
__global__ __launch_bounds__(256) void refine_combine(const float* __restrict__ partial,
                                                      const float* __restrict__ x,
                                                      const float* __restrict__ wf,
                                                      const float* __restrict__ be,
                                                      const int* __restrict__ flags,
                                                      float* __restrict__ out) {
    int count = flags[0]; if (count > FLAG_CAP) count = FLAG_CAP;
    const int i = blockIdx.x;
    if (i >= count) return;
    const int t = flags[1 + i];
    const int tid = threadIdx.x;
    const float4 wq = *(const float4*)(wf + (size_t)i * 4);
#pragma unroll
    for (int c = 0; c < 3; ++c) {
        const int col = (c * 256 + tid) * 4;
        float4 s = *(const float4*)(x + (size_t)t * H + col);
#pragma unroll
        for (int ez = 0; ez < EXPERTS * KSPLIT; ++ez) {
            float4 p = *(const float4*)(partial + ((size_t)ez * FLAG_CAP + i) * H + col);
            s.x += p.x; s.y += p.y; s.z += p.z; s.w += p.w;
        }
        const float4 b0 = *(const float4*)(be + 0 * H + col);
        const float4 b1 = *(const float4*)(be + 1 * H + col);
        const float4 b2 = *(const float4*)(be + 2 * H + col);
        const float4 b3 = *(const float4*)(be + 3 * H + col);
        s.x += wq.x * b0.x + wq.y * b1.x + wq.z * b2.x + wq.w * b3.x;
        s.y += wq.x * b0.y + wq.y * b1.y + wq.z * b2.y + wq.w * b3.y;
        s.z += wq.x * b0.z + wq.y * b1.z + wq.z * b2.z + wq.w * b3.z;
        s.w += wq.x * b0.w + wq.y * b1.w + wq.z * b2.w + wq.w * b3.w;
        *(float4*)(out + (size_t)t * H + col) = s;
    }
}

// ---------------------------------------------------------------------------
// Kernel 3: bucketed top-2 GEMM, BKG=64 (unchanged from r10 — at the
// documented m97-structure ceiling, ~905 TF effective).
// ---------------------------------------------------------------------------
__global__ __launch_bounds__(256, 4) void moe_gemm_b(const bf16* __restrict__ zA,
                                                     const bf16* __restrict__ zB,
                                                     const bf16* __restrict__ Wt,
                                                     const int* __restrict__ tokslot,
                                                     const float* __restrict__ wbuf,
                                                     const int* __restrict__ tile_bkt,
                                                     const int* __restrict__ tile_end,
                                                     const float* __restrict__ xin,
                                                     const float* __restrict__ be,
                                                     float* __restrict__ out) {
    const int tile = blockIdx.y;
    const int b = tile_bkt[tile];
    if (b < 0) return;
    const int ea = pair_a(b);
    const int eb = pair_b(b);
    const int endSlot = tile_end[tile];

    __shared__ __align__(16) bf16 As[BM * BKG];
    __shared__ __align__(16) bf16 Bs[BN * BKG];
    __shared__ __align__(16) float wlds[BM * 4];
    __shared__ int tlds[BM];

    const int tid  = threadIdx.x;
    const int wid  = tid >> 6;
    const int lane = tid & 63;
    const int wm   = wid >> 1;
    const int wn   = wid & 1;
    const int tileM = tile * BM;
    const int tileN = blockIdx.x * BN;

    if (tid < 128) {
        const int tk = tokslot[tileM + tid];
        tlds[tid] = tk;
        *(float4*)&wlds[tid * 4] = *(const float4*)(wbuf + (size_t)tk * 4);
    }

    const int srow   = lane >> 3;
    const int schunk = (((lane & 7) ^ ((lane >> 3) & 7)) * 8);
    const int lrow   = lane & 15;
    const int rx     = lane >> 4;
    const int r0   = wm * 64 + (lane >> 4) * 4;
    const int c0   = tileN + wn * 64 + (lane & 15);

    f32x4 acc[4][4];
#pragma unroll
    for (int m = 0; m < 4; ++m)
#pragma unroll
        for (int n = 0; n < 4; ++n)
            acc[m][n] = (f32x4){0.f, 0.f, 0.f, 0.f};

    for (int ph = 0; ph < 2; ++ph) {
        const bf16* Asrc = ph ? zB : zA;
        const int ex = ph ? eb : ea;
        const bf16* Bbase = Wt + ((size_t)ex * H + tileN) * H;

        for (int k0 = 0; k0 < H; k0 += BKG) {
            __syncthreads();
#pragma unroll
            for (int i = 0; i < 4; ++i) {
                const int rr = wid * 32 + i * 8;
                gload_lds16(Asrc + (size_t)(tileM + rr + srow) * H + k0 + schunk,
                            As + (size_t)rr * BKG);
                gload_lds16(Bbase + (size_t)(rr + srow) * H + k0 + schunk,
                            Bs + (size_t)rr * BKG);
            }
            __syncthreads();

#pragma unroll
            for (int ks = 0; ks < 2; ++ks) {
                bf16x8 a[4], bfr[4];
#pragma unroll
                for (int m = 0; m < 4; ++m) {
                    const int row = wm * 64 + m * 16 + lrow;
                    const int ch = ((ks * 4 + rx) ^ (lrow & 7)) * 8;
                    a[m] = *(const bf16x8*)&As[row * BKG + ch];
                }
#pragma unroll
                for (int n = 0; n < 4; ++n) {
                    const int row = wn * 64 + n * 16 + lrow;
                    const int ch = ((ks * 4 + rx) ^ (lrow & 7)) * 8;
                    bfr[n] = *(const bf16x8*)&Bs[row * BKG + ch];
                }
#pragma unroll
                for (int m = 0; m < 4; ++m)
#pragma unroll
                    for (int n = 0; n < 4; ++n)
                        acc[m][n] = __builtin_amdgcn_mfma_f32_16x16x32_bf16(a[m], bfr[n], acc[m][n], 0, 0, 0);
            }
        }
    }

    float bev[4][4];
#pragma unroll
    for (int n = 0; n < 4; ++n)
#pragma unroll
        for (int e = 0; e < 4; ++e)
            bev[n][e] = be[(size_t)e * H + c0 + n * 16];

#pragma unroll
    for (int m = 0; m < 4; ++m) {
#pragma unroll
        for (int r = 0; r < 4; ++r) {
            const int tl = r0 + m * 16 + r;
            const int slotg = tileM + tl;
            if (slotg < endSlot) {
                const size_t t = (size_t)tlds[tl];
                const float4 wq = *(const float4*)&wlds[tl * 4];
                const float* xr = xin + t * H;
                float* orow = out + t * H;
#pragma unroll
                for (int n = 0; n < 4; ++n) {
                    const int col = c0 + n * 16;
                    const float bias = wq.x * bev[n][0] + wq.y * bev[n][1] +
                                       wq.z * bev[n][2] + wq.w * bev[n][3];
                    orow[col] = xr[col] + acc[m][n][r] + bias;
                }
            }
        }
    }
}

// ---------------------------------------------------------------------------
extern "C" void kernel_launch(void* const* d_in, const int* in_sizes, int n_in,
                              void* d_out, int out_size, void* d_ws, size_t ws_size,
                              hipStream_t stream) {
    (void)in_sizes; (void)n_in; (void)out_size; (void)ws_size;

    const float* x    = (const float*)d_in[0];
    const float* ln_g = (const float*)d_in[1];
    const float* ln_b = (const float*)d_in[2];
    const float* Wr   = (const float*)d_in[3];
    const float* br   = (const float*)d_in[4];
    const float* We   = (const float*)d_in[5];
    const float* be   = (const float*)d_in[6];
    float* out = (float*)d_out;

    uint8_t* ws = (uint8_t*)d_ws;
    const size_t zBytes   = (size_t)MTOK * H * 2;
    const size_t wtBytes  = (size_t)EXPERTS * H * H * 2;
    const size_t wbBytes  = (size_t)MTOK * 4 * 4;
    const size_t zcBytes  = (size_t)FLAG_CAP * H * 2;
    const size_t wfBytes  = (size_t)(FLAG_CAP + 128) * 4 * 4;
    const size_t flgBytes = 8192;
    const size_t zsBytes  = (size_t)NT_MAX * BM * H * 2;   // 55 MB each

    bf16*  z    = (bf16*)ws;                                       ws += zBytes;
    bf16*  WtH  = (bf16*)ws;                                       ws += wtBytes;
    bf16*  WtL  = (bf16*)ws;                                       ws += wtBytes;
    float* wb   = (float*)ws;                                      ws += wbBytes;
    bf16*  zcH  = (bf16*)ws;                                       ws += zcBytes;
    bf16*  zcL  = (bf16*)ws;                                       ws += zcBytes;
    float* wf   = (float*)ws;                                      ws += wfBytes;
    int*   flg  = (int*)ws;                                        ws += flgBytes;
    bf16*  zA   = (bf16*)ws;                                       ws += zsBytes;
    bf16*  zB   = (bf16*)ws;                                       ws += zsBytes;
    int*   bkt  = (int*)ws;                                        ws += (size_t)MTOK * 4;
    int*   tokslot = (int*)ws;                                     ws += (size_t)NT_MAX * BM * 4;
    int*   bcount  = (int*)ws;                                     ws += 256;
    int*   off_g   = (int*)ws;                                     ws += 256;
    int*   tile_bkt = (int*)ws;                                    ws += 1024;
    int*   tile_end = (int*)ws;                                    ws += 1024;
    int*   cursor = bcount + 6;
    // refine partials: 8 slabs x FLAG_CAP x H fp32 = 100.7 MB, spans zA+zB
    // (both regenerated by layer-2 scatter_scale after refine_combine).
    float* partial = (float*)zA;

    const dim3 gemm_grid(H / BN, NT_MAX);

    // ---- layer 1 ----
    we_transpose<1><<<dim3(H / 64, H / 64, EXPERTS), 256, 0, stream>>>(We, WtH, WtL);
    zero12<<<1, 64, 0, stream>>>(bcount);
    ln_router_k<0><<<dim3(MTOK), 256, 0, stream>>>(x, ln_g, ln_b, Wr, br, z, wb, bkt, bcount, flg);
    bucket_scan<<<1, 256, 0, stream>>>(bcount, off_g, tile_bkt, tile_end, tokslot);
    scatter_scale<<<dim3(MTOK), 384, 0, stream>>>(z, wb, bkt, off_g, cursor, tokslot, zA, zB);
    moe_gemm_b<<<gemm_grid, 256, 0, stream>>>(zA, zB, WtH, tokslot, wb, tile_bkt, tile_end, x, be, out);

    // ---- selective fp32-class refinement for near-tie layer-2 routing ----
    zero_flags<<<1, 64, 0, stream>>>(flg);
    ln_router_k<1><<<dim3(MTOK), 256, 0, stream>>>(out, ln_g + H, ln_b + H,
                                                   Wr + (size_t)H * EXPERTS, br + EXPERTS,
                                                   z, wb, bkt, bcount, flg);
    zfill<<<dim3(FLAG_CAP), 256, 0, stream>>>(x, ln_g, ln_b, flg, wb, zcH, zcL, wf);
    refine_mfma<<<dim3(H / BN, FLAG_CAP / RBM, EXPERTS * KSPLIT), 256, 0, stream>>>(
        zcH, zcL, WtH, WtL, wf, flg, partial);
    refine_combine<<<dim3(FLAG_CAP), 256, 0, stream>>>(partial, x, wf, be, flg, out);

    // ---- layer 2 ----
    we_transpose<0><<<dim3(H / 64, H / 64, EXPERTS), 256, 0, stream>>>(
        We + (size_t)EXPERTS * H * H, WtH, WtL);
    zero12<<<1, 64, 0, stream>>>(bcount);
    ln_router_k<0><<<dim3(MTOK), 256, 0, stream>>>(out, ln_g + H, ln_b + H,
                                                   Wr + (size_t)H * EXPERTS, br + EXPERTS,
                                                   z, wb, bkt, bcount, flg);
    bucket_scan<<<1, 256, 0, stream>>>(bcount, off_g, tile_bkt, tile_end, tokslot);
    scatter_scale<<<dim3(MTOK), 384, 0, stream>>>(z, wb, bkt, off_g, cursor, tokslot, zA, zB);
    moe_gemm_b<<<gemm_grid, 256, 0, stream>>>(zA, zB, WtH, tokslot, wb, tile_bkt, tile_end, out,
                                              be + (size_t)EXPERTS * H, out);
}

// Round 12
// 1342.055 us; speedup vs baseline: 1.0382x; 1.0382x over previous
//
#include <hip/hip_runtime.h>
#include <hip/hip_bf16.h>
#include <stdint.h>

#define H 3072
#define EXPERTS 4
#define MTOK 8192          // B*T
#define LN_EPS 1e-5f
#define FLAG_CAP 1024
#define TAU 0.03f          // layer-2 router logit gap threshold for refinement
#define NT_MAX 70          // max M-tiles after per-bucket 128-padding
#define KSPLIT 2           // refine split-K factor

#define BM 128
#define BN 128
#define BK 32              // refine kernel K-step
#define BKG 64             // main gemm K-step (halves barrier count vs 32)

typedef __bf16 bf16;
typedef __bf16 bf16x8 __attribute__((ext_vector_type(8)));
typedef __bf16 bf16x4 __attribute__((ext_vector_type(4)));
typedef float  f32x4  __attribute__((ext_vector_type(4)));

typedef const __attribute__((address_space(1))) unsigned char* gas1p;
typedef __attribute__((address_space(3))) unsigned char* las3p;

__device__ __forceinline__ void gload_lds16(const void* g, void* l) {
    __builtin_amdgcn_global_load_lds((gas1p)g, (las3p)l, 16, 0, 0);
}

__device__ __forceinline__ int pair_a(int b) { return b < 3 ? 0 : (b < 5 ? 1 : 2); }
__device__ __forceinline__ int pair_b(int b) { return b < 3 ? b + 1 : (b < 5 ? b - 1 : 3); }

// ---------------------------------------------------------------------------
// Kernel 1: We fp32 [E][K][N] -> Wt_hi/Wt_lo bf16 [E][N][K] (split transpose)
// ---------------------------------------------------------------------------
template <int WLO>
__global__ __launch_bounds__(256) void we_transpose(const float* __restrict__ We,
                                                    bf16* __restrict__ Wt_hi,
                                                    bf16* __restrict__ Wt_lo) {
    __shared__ float tile[64][65];
    const int e  = blockIdx.z;
    const int k0 = blockIdx.y * 64;
    const int n0 = blockIdx.x * 64;
    const int tid = threadIdx.x;

    const float* src = We + ((size_t)e * H + k0) * H + n0;
    const int kl = tid >> 4;
    const int nl = (tid & 15) * 4;
#pragma unroll
    for (int it = 0; it < 4; ++it) {
        float4 v = *(const float4*)(src + (size_t)(kl + it * 16) * H + nl);
        tile[kl + it * 16][nl + 0] = v.x;
        tile[kl + it * 16][nl + 1] = v.y;
        tile[kl + it * 16][nl + 2] = v.z;
        tile[kl + it * 16][nl + 3] = v.w;
    }
    __syncthreads();
    const size_t dbase = ((size_t)e * H + n0) * H + k0;
    const int nl2 = tid >> 4;
    const int kl2 = (tid & 15) * 4;
#pragma unroll
    for (int it = 0; it < 4; ++it) {
        bf16x4 oh, ol;
#pragma unroll
        for (int j = 0; j < 4; ++j) {
            float v = tile[kl2 + j][nl2 + it * 16];
            bf16 hi = (bf16)v;
            oh[j] = hi;
            ol[j] = (bf16)(v - (float)hi);
        }
        const size_t doff = dbase + (size_t)(nl2 + it * 16) * H + kl2;
        *(bf16x4*)(Wt_hi + doff) = oh;
        if (WLO) *(bf16x4*)(Wt_lo + doff) = ol;
    }
}

// ---------------------------------------------------------------------------
// Kernel 2: LayerNorm (fp32, two-pass var) + router per token.
// MODE 0: write z bf16, w fp32, bucket id + count.  MODE 1: flag near-ties.
// ---------------------------------------------------------------------------
template <int MODE>
__global__ __launch_bounds__(256) void ln_router_k(const float* __restrict__ xin,
                                                   const float* __restrict__ gamma,
                                                   const float* __restrict__ beta,
                                                   const float* __restrict__ Wr,   // [H][4]
                                                   const float* __restrict__ br,   // [4]
                                                   bf16* __restrict__ z,
                                                   float* __restrict__ wout,
                                                   int* __restrict__ bkt,
                                                   int* __restrict__ bcount,
                                                   int* __restrict__ flags) {
    __shared__ float red[4][4];
    __shared__ float bc[2];

    const int t    = blockIdx.x;
    const int tid  = threadIdx.x;
    const int wid  = tid >> 6;
    const int lane = tid & 63;
    const float* xrow = xin + (size_t)t * H;

    float4 xv[3];
    float s = 0.f;
#pragma unroll
    for (int c = 0; c < 3; ++c) {
        xv[c] = *(const float4*)(xrow + (c * 256 + tid) * 4);
        s += xv[c].x + xv[c].y + xv[c].z + xv[c].w;
    }
#pragma unroll
    for (int off = 32; off; off >>= 1) s += __shfl_down(s, off);
    if (lane == 0) red[wid][0] = s;
    __syncthreads();
    if (tid == 0) bc[0] = (red[0][0] + red[1][0] + red[2][0] + red[3][0]) * (1.f / (float)H);
    __syncthreads();
    const float mu = bc[0];

    float d = 0.f;
#pragma unroll
    for (int c = 0; c < 3; ++c) {
        float dx;
        dx = xv[c].x - mu; d += dx * dx;
        dx = xv[c].y - mu; d += dx * dx;
        dx = xv[c].z - mu; d += dx * dx;
        dx = xv[c].w - mu; d += dx * dx;
    }
#pragma unroll
    for (int off = 32; off; off >>= 1) d += __shfl_down(d, off);
    if (lane == 0) red[wid][1] = d;
    __syncthreads();
    if (tid == 0) {
        float var = (red[0][1] + red[1][1] + red[2][1] + red[3][1]) * (1.f / (float)H);
        bc[1] = 1.f / sqrtf(var + LN_EPS);
    }
    __syncthreads();
    const float rs = bc[1];

    float l0 = 0.f, l1 = 0.f, l2 = 0.f, l3 = 0.f;
    bf16* zrow = z + (size_t)t * H;
#pragma unroll
    for (int c = 0; c < 3; ++c) {
        const int i0 = (c * 256 + tid) * 4;
        float4 gv = *(const float4*)(gamma + i0);
        float4 bv = *(const float4*)(beta + i0);
        float zz[4];
        zz[0] = (xv[c].x - mu) * rs * gv.x + bv.x;
        zz[1] = (xv[c].y - mu) * rs * gv.y + bv.y;
        zz[2] = (xv[c].z - mu) * rs * gv.z + bv.z;
        zz[3] = (xv[c].w - mu) * rs * gv.w + bv.w;
        if (MODE == 0) {
            bf16x4 zb = { (bf16)zz[0], (bf16)zz[1], (bf16)zz[2], (bf16)zz[3] };
            *(bf16x4*)(zrow + i0) = zb;
        }
#pragma unroll
        for (int j = 0; j < 4; ++j) {
            float4 wr = *(const float4*)(Wr + (size_t)(i0 + j) * 4);
            l0 += zz[j] * wr.x; l1 += zz[j] * wr.y;
            l2 += zz[j] * wr.z; l3 += zz[j] * wr.w;
        }
    }
    __syncthreads();
#pragma unroll
    for (int off = 32; off; off >>= 1) {
        l0 += __shfl_down(l0, off);
        l1 += __shfl_down(l1, off);
        l2 += __shfl_down(l2, off);
        l3 += __shfl_down(l3, off);
    }
    if (lane == 0) { red[wid][0] = l0; red[wid][1] = l1; red[wid][2] = l2; red[wid][3] = l3; }
    __syncthreads();
    if (tid == 0) {
        float lf[4];
#pragma unroll
        for (int e = 0; e < 4; ++e)
            lf[e] = red[0][e] + red[1][e] + red[2][e] + red[3][e] + br[e];
        if (MODE == 0) {
            float mx = fmaxf(fmaxf(lf[0], lf[1]), fmaxf(lf[2], lf[3]));
            float p[4]; float ps = 0.f;
#pragma unroll
            for (int e = 0; e < 4; ++e) { p[e] = expf(lf[e] - mx); ps += p[e]; }
#pragma unroll
            for (int e = 0; e < 4; ++e) p[e] /= ps;
            int i1 = 0; float v1 = p[0];
#pragma unroll
            for (int e = 1; e < 4; ++e) if (p[e] > v1) { v1 = p[e]; i1 = e; }
            int i2 = -1; float v2 = -1.f;
#pragma unroll
            for (int e = 0; e < 4; ++e) if (e != i1 && p[e] > v2) { v2 = p[e]; i2 = e; }
            const float den = fmaxf(v1 + v2, 1e-8f);
            float w4[4] = {0.f, 0.f, 0.f, 0.f};
            w4[i1] = v1 / den;
            w4[i2] = v2 / den;
            *(float4*)(wout + (size_t)t * 4) = make_float4(w4[0], w4[1], w4[2], w4[3]);
            const int lo = min(i1, i2), hi = max(i1, i2);
            const int b = (lo == 0) ? hi - 1 : (lo == 1 ? hi + 1 : 5);
            bkt[t] = b;
            atomicAdd(&bcount[b], 1);
        } else {
            float a = lf[0], b = lf[1], c = lf[2], dd = lf[3], t1;
#define SW_(p,q) if (p < q) { t1 = p; p = q; q = t1; }
            SW_(a, b) SW_(c, dd) SW_(a, c) SW_(b, dd) SW_(b, c)
#undef SW_
            if (b - c < TAU) {
                int idx = atomicAdd(flags, 1);
                if (idx < FLAG_CAP) flags[1 + idx] = t;
            }
        }
    }
}

__global__ void zero_flags(int* flags) { if (threadIdx.x == 0) flags[0] = 0; }
__global__ void zero12(int* bcount) { if (threadIdx.x < 12) bcount[threadIdx.x] = 0; }

// ---------------------------------------------------------------------------
// bucket_scan: 1 block. Padded-prefix offsets, per-tile bucket/end tables.
// ---------------------------------------------------------------------------
__global__ __launch_bounds__(256) void bucket_scan(const int* __restrict__ bcount,
                                                   int* __restrict__ off_g,
                                                   int* __restrict__ tile_bkt,
                                                   int* __restrict__ tile_end,
                                                   int* __restrict__ tokslot) {
    for (int i = threadIdx.x; i < NT_MAX * BM; i += 256) tokslot[i] = 0;
    if (threadIdx.x == 0) {
        int off = 0, tile = 0;
        for (int b = 0; b < 6; ++b) {
            off_g[b] = off;
            const int c = bcount[b];
            const int ntb = (c + BM - 1) / BM;
            for (int k = 0; k < ntb; ++k) { tile_bkt[tile] = b; tile_end[tile] = off + c; ++tile; }
            off += ntb * BM;
        }
        for (; tile < NT_MAX; ++tile) { tile_bkt[tile] = -1; tile_end[tile] = 0; }
    }
}

__global__ __launch_bounds__(256) void scatter(const int* __restrict__ bkt,
                                               const int* __restrict__ off_g,
                                               int* __restrict__ cursor,
                                               int* __restrict__ tokslot,
                                               int* __restrict__ slot_of) {
    const int t = blockIdx.x * 256 + threadIdx.x;
    if (t >= MTOK) return;
    const int b = bkt[t];
    const int slot = off_g[b] + atomicAdd(&cursor[b], 1);
    tokslot[slot] = t;
    slot_of[t] = slot;
}

// ---------------------------------------------------------------------------
// scatter_scale: zA[slot] = w_a * z[t], zB[slot] = w_b * z[t]  (bf16)
// ---------------------------------------------------------------------------
__global__ __launch_bounds__(384) void scatter_scale(const bf16* __restrict__ z,
                                                     const float* __restrict__ wb,
                                                     const int* __restrict__ bkt,
                                                     const int* __restrict__ slot_of,
                                                     bf16* __restrict__ zA,
                                                     bf16* __restrict__ zB) {
    const int t = blockIdx.x;
    const int b = bkt[t];
    const float wa = wb[(size_t)t * 4 + pair_a(b)];
    const float wv = wb[(size_t)t * 4 + pair_b(b)];
    const size_t slot = (size_t)slot_of[t];
    const int i0 = threadIdx.x * 8;
    const bf16x8 v = *(const bf16x8*)(z + (size_t)t * H + i0);
    bf16x8 ra, rb;
#pragma unroll
    for (int j = 0; j < 8; ++j) {
        const float f = (float)v[j];
        ra[j] = (bf16)(f * wa);
        rb[j] = (bf16)(f * wv);
    }
    *(bf16x8*)(zA + slot * H + i0) = ra;
    *(bf16x8*)(zB + slot * H + i0) = rb;
}

// ---------------------------------------------------------------------------
// zfill: fp32 layer-1 LN for flagged tokens -> compact hi/lo bf16 rows + w1.
// ---------------------------------------------------------------------------
__global__ __launch_bounds__(256) void zfill(const float* __restrict__ x,
                                             const float* __restrict__ gamma,
                                             const float* __restrict__ beta,
                                             const int* __restrict__ flags,
                                             const float* __restrict__ wb,
                                             bf16* __restrict__ zc_hi,
                                             bf16* __restrict__ zc_lo,
                                             float* __restrict__ wfo) {
    __shared__ float red[4][2];
    __shared__ float bc[2];
    const int i = blockIdx.x;
    int count = flags[0]; if (count > FLAG_CAP) count = FLAG_CAP;
    if (i >= count) return;
    const int t = flags[1 + i];
    const int tid = threadIdx.x, wid = tid >> 6, lane = tid & 63;
    const float* xrow = x + (size_t)t * H;

    float4 xv[3]; float s = 0.f;
#pragma unroll
    for (int c = 0; c < 3; ++c) {
        xv[c] = *(const float4*)(xrow + (c * 256 + tid) * 4);
        s += xv[c].x + xv[c].y + xv[c].z + xv[c].w;
    }
#pragma unroll
    for (int off = 32; off; off >>= 1) s += __shfl_down(s, off);
    if (lane == 0) red[wid][0] = s;
    __syncthreads();
    if (tid == 0) bc[0] = (red[0][0] + red[1][0] + red[2][0] + red[3][0]) * (1.f / (float)H);
    __syncthreads();
    const float mu = bc[0];
    float d = 0.f;
#pragma unroll
    for (int c = 0; c < 3; ++c) {
        float dx;
        dx = xv[c].x - mu; d += dx * dx;
        dx = xv[c].y - mu; d += dx * dx;
        dx = xv[c].z - mu; d += dx * dx;
        dx = xv[c].w - mu; d += dx * dx;
    }
#pragma unroll
    for (int off = 32; off; off >>= 1) d += __shfl_down(d, off);
    if (lane == 0) red[wid][1] = d;
    __syncthreads();
    if (tid == 0) bc[1] = 1.f / sqrtf((red[0][1] + red[1][1] + red[2][1] + red[3][1]) * (1.f / (float)H) + LN_EPS);
    __syncthreads();
    const float rs = bc[1];

    bf16* zh = zc_hi + (size_t)i * H;
    bf16* zl = zc_lo + (size_t)i * H;
#pragma unroll
    for (int c = 0; c < 3; ++c) {
        const int i0 = (c * 256 + tid) * 4;
        float4 gv = *(const float4*)(gamma + i0);
        float4 bv = *(const float4*)(beta + i0);
        float vv[4];
        vv[0] = (xv[c].x - mu) * rs * gv.x + bv.x;
        vv[1] = (xv[c].y - mu) * rs * gv.y + bv.y;
        vv[2] = (xv[c].z - mu) * rs * gv.z + bv.z;
        vv[3] = (xv[c].w - mu) * rs * gv.w + bv.w;
        bf16x4 oh, ol;
#pragma unroll
        for (int j = 0; j < 4; ++j) {
            bf16 hi = (bf16)vv[j];
            oh[j] = hi;
            ol[j] = (bf16)(vv[j] - (float)hi);
        }
        *(bf16x4*)(zh + i0) = oh;
        *(bf16x4*)(zl + i0) = ol;
    }
    if (tid == 0) *(float4*)(wfo + (size_t)i * 4) = *(const float4*)(wb + (size_t)t * 4);
}

// ---------------------------------------------------------------------------
// refine_mfma: split-K per-expert partials, hi/lo split MFMA, double-buffered
// staging, swizzled LDS. grid (H/BN, FLAG_CAP/BM, EXPERTS*KSPLIT).
// ---------------------------------------------------------------------------
__global__ __launch_bounds__(256) void refine_mfma(const bf16* __restrict__ zc_hi,
                                                   const bf16* __restrict__ zc_lo,
                                                   const bf16* __restrict__ Wt_hi,
                                                   const bf16* __restrict__ Wt_lo,
                                                   const float* __restrict__ wf,
                                                   const int* __restrict__ flags,
                                                   float* __restrict__ partial) {
    int count = flags[0]; if (count > FLAG_CAP) count = FLAG_CAP;
    const int tileM = blockIdx.y * BM;
    if (tileM >= count) return;
    const int ez = blockIdx.z;          // e*KSPLIT + ks
    const int e  = ez >> 1;
    const int ks = ez & 1;
    const int kbeg = ks * (H / KSPLIT / BK);
    const int kend = kbeg + H / KSPLIT / BK;

    __shared__ __align__(16) bf16 Ah[2][BM * BK];
    __shared__ __align__(16) bf16 Al[2][BM * BK];
    __shared__ __align__(16) bf16 Bh[2][BN * BK];
    __shared__ __align__(16) bf16 Bl[2][BN * BK];
    __shared__ float wlds[BM];

    const int tid  = threadIdx.x;
    const int wid  = tid >> 6;
    const int lane = tid & 63;
    const int wm   = wid >> 1;
    const int wn   = wid & 1;
    const int tileN = blockIdx.x * BN;

    if (tid < BM) wlds[tid] = wf[(size_t)(tileM + tid) * 4 + e];

    const int srow   = lane >> 2;
    const int schunk = (((lane & 3) ^ ((lane >> 3) & 3)) * 8);
    const int lrow   = lane & 15;
    const int rchunk = (((lane >> 4) ^ ((lane >> 1) & 3)) * 8);
    const int r0   = wm * 64 + (lane >> 4) * 4;
    const int c0   = tileN + wn * 64 + (lane & 15);

    const bf16* Ahb = zc_hi;
    const bf16* Alb = zc_lo;
    const bf16* Bhb = Wt_hi + ((size_t)e * H + tileN) * H;
    const bf16* Blb = Wt_lo + ((size_t)e * H + tileN) * H;

#define RSTAGE(buf, kk0)                                                              \
    _Pragma("unroll")                                                                 \
    for (int i_ = 0; i_ < 2; ++i_) {                                                  \
        const int rr_ = wid * 32 + i_ * 16;                                           \
        gload_lds16(Ahb + (size_t)(tileM + rr_ + srow) * H + (kk0) + schunk,          \
                    &Ah[buf][(size_t)rr_ * BK]);                                      \
        gload_lds16(Alb + (size_t)(tileM + rr_ + srow) * H + (kk0) + schunk,          \
                    &Al[buf][(size_t)rr_ * BK]);                                      \
        gload_lds16(Bhb + (size_t)(rr_ + srow) * H + (kk0) + schunk,                  \
                    &Bh[buf][(size_t)rr_ * BK]);                                      \
        gload_lds16(Blb + (size_t)(rr_ + srow) * H + (kk0) + schunk,                  \
                    &Bl[buf][(size_t)rr_ * BK]);                                      \
    }

    f32x4 acc[4][4];
#pragma unroll
    for (int m = 0; m < 4; ++m)
#pragma unroll
        for (int n = 0; n < 4; ++n)
            acc[m][n] = (f32x4){0.f, 0.f, 0.f, 0.f};

    RSTAGE(0, kbeg * BK)
    __syncthreads();

    int cur = 0;
    for (int kk = kbeg; kk < kend; ++kk) {
        if (kk + 1 < kend) { RSTAGE(cur ^ 1, (kk + 1) * BK) }

        bf16x8 ah[4], al[4], bh[4], bl[4];
#pragma unroll
        for (int m = 0; m < 4; ++m) {
            ah[m] = *(const bf16x8*)&Ah[cur][(wm * 64 + m * 16 + lrow) * BK + rchunk];
            al[m] = *(const bf16x8*)&Al[cur][(wm * 64 + m * 16 + lrow) * BK + rchunk];
        }
#pragma unroll
        for (int n = 0; n < 4; ++n) {
            bh[n] = *(const bf16x8*)&Bh[cur][(wn * 64 + n * 16 + lrow) * BK + rchunk];
            bl[n] = *(const bf16x8*)&Bl[cur][(wn * 64 + n * 16 + lrow) * BK + rchunk];
        }
#pragma unroll
        for (int m = 0; m < 4; ++m)
#pragma unroll
            for (int n = 0; n < 4; ++n) {
                acc[m][n] = __builtin_amdgcn_mfma_f32_16x16x32_bf16(al[m], bh[n], acc[m][n], 0, 0, 0);
                acc[m][n] = __builtin_amdgcn_mfma_f32_16x16x32_bf16(ah[m], bl[n], acc[m][n], 0, 0, 0);
                acc[m][n] = __builtin_amdgcn_mfma_f32_16x16x32_bf16(ah[m], bh[n], acc[m][n], 0, 0, 0);
            }
        __syncthreads();
        cur ^= 1;
    }
#undef RSTAGE

#pragma unroll
    for (int m = 0; m < 4; ++m) {
#pragma unroll
        for (int r = 0; r < 4; ++r) {
            const int tl = r0 + m * 16 + r;
            const int g = tileM + tl;
            if (g < count) {
                const float w = wlds[tl];
                float* prow = partial + ((size_t)ez * FLAG_CAP + g) * H;
#pragma unroll
                for (int n = 0; n < 4; ++n)
                    prow[c0 + n * 16] = w * acc[m][n][r];
            }
        }
    }
}

// ---------------------------------------------------------------------------
// refine_combine: out[t] = x[t] + sum_ez partial[ez][i] + sum_e w_e*be_e
// ---------------------------------------------------------------------------
__global__ __launch_bounds__(256) void refine_combine(const float* __restrict__ partial,
                                                      const float* __restrict__ x,
                                                      const float* __restrict__ wf,
                                                      const float* __restrict__ be,
                                                      const int* __restrict__ flags,
                                                      float* __restrict__ out) {
    int count = flags[0]; if (count > FLAG_CAP) count = FLAG_CAP;
    const int i = blockIdx.x;
    if (i >= count) return;
    const int t = flags[1 + i];
    const int tid = threadIdx.x;
    const float4 wq = *(const float4*)(wf + (size_t)i * 4);
#pragma unroll
    for (int c = 0; c < 3; ++c) {
        const int col = (c * 256 + tid) * 4;
        float4 s = *(const float4*)(x + (size_t)t * H + col);
#pragma unroll
        for (int ez = 0; ez < EXPERTS * KSPLIT; ++ez) {
            float4 p = *(const float4*)(partial + ((size_t)ez * FLAG_CAP + i) * H + col);
            s.x += p.x; s.y += p.y; s.z += p.z; s.w += p.w;
        }
        const float4 b0 = *(const float4*)(be + 0 * H + col);
        const float4 b1 = *(const float4*)(be + 1 * H + col);
        const float4 b2 = *(const float4*)(be + 2 * H + col);
        const float4 b3 = *(const float4*)(be + 3 * H + col);
        s.x += wq.x * b0.x + wq.y * b1.x + wq.z * b2.x + wq.w * b3.x;
        s.y += wq.x * b0.y + wq.y * b1.y + wq.z * b2.y + wq.w * b3.y;
        s.z += wq.x * b0.z + wq.y * b1.z + wq.z * b2.z + wq.w * b3.z;
        s.w += wq.x * b0.w + wq.y * b1.w + wq.z * b2.w + wq.w * b3.w;
        *(float4*)(out + (size_t)t * H + col) = s;
    }
}

// ---------------------------------------------------------------------------
// Kernel 3: bucketed top-2 GEMM, BKG=64: half the barrier-pairs of BK=32,
// 32 MFMAs per drain. Two k-slices processed sequentially so live frags stay
// a[4]+b[4] (32 VGPR) -> fits the (256,4) 128-reg cap. 8-chunk swizzle:
// LDS[row][c] = global chunk c ^ (row&7); both sides use the same involution.
// At the m97-structure ceiling (~905 TF effective, MfmaUtil ~38%).
// ---------------------------------------------------------------------------
__global__ __launch_bounds__(256, 4) void moe_gemm_b(const bf16* __restrict__ zA,
                                                     const bf16* __restrict__ zB,
                                                     const bf16* __restrict__ Wt,
                                                     const int* __restrict__ tokslot,
                                                     const float* __restrict__ wbuf,
                                                     const int* __restrict__ tile_bkt,
                                                     const int* __restrict__ tile_end,
                                                     const float* __restrict__ xin,
                                                     const float* __restrict__ be,
                                                     float* __restrict__ out) {
    const int tile = blockIdx.y;
    const int b = tile_bkt[tile];
    if (b < 0) return;
    const int ea = pair_a(b);
    const int eb = pair_b(b);
    const int endSlot = tile_end[tile];

    __shared__ __align__(16) bf16 As[BM * BKG];
    __shared__ __align__(16) bf16 Bs[BN * BKG];
    __shared__ __align__(16) float wlds[BM * 4];
    __shared__ int tlds[BM];

    const int tid  = threadIdx.x;
    const int wid  = tid >> 6;
    const int lane = tid & 63;
    const int wm   = wid >> 1;
    const int wn   = wid & 1;
    const int tileM = tile * BM;
    const int tileN = blockIdx.x * BN;

    if (tid < 128) {
        const int tk = tokslot[tileM + tid];
        tlds[tid] = tk;
        *(float4*)&wlds[tid * 4] = *(const float4*)(wbuf + (size_t)tk * 4);
    }

    const int srow   = lane >> 3;
    const int schunk = (((lane & 7) ^ ((lane >> 3) & 7)) * 8);
    const int lrow   = lane & 15;
    const int rx     = lane >> 4;
    const int r0   = wm * 64 + (lane >> 4) * 4;
    const int c0   = tileN + wn * 64 + (lane & 15);

    f32x4 acc[4][4];
#pragma unroll
    for (int m = 0; m < 4; ++m)
#pragma unroll
        for (int n = 0; n < 4; ++n)
            acc[m][n] = (f32x4){0.f, 0.f, 0.f, 0.f};

    for (int ph = 0; ph < 2; ++ph) {
        const bf16* Asrc = ph ? zB : zA;
        const int ex = ph ? eb : ea;
        const bf16* Bbase = Wt + ((size_t)ex * H + tileN) * H;

        for (int k0 = 0; k0 < H; k0 += BKG) {
            __syncthreads();
#pragma unroll
            for (int i = 0; i < 4; ++i) {
                const int rr = wid * 32 + i * 8;
                gload_lds16(Asrc + (size_t)(tileM + rr + srow) * H + k0 + schunk,
                            As + (size_t)rr * BKG);
                gload_lds16(Bbase + (size_t)(rr + srow) * H + k0 + schunk,
                            Bs + (size_t)rr * BKG);
            }
            __syncthreads();

#pragma unroll
            for (int ks = 0; ks < 2; ++ks) {
                bf16x8 a[4], bfr[4];
#pragma unroll
                for (int m = 0; m < 4; ++m) {
                    const int row = wm * 64 + m * 16 + lrow;
                    const int ch = ((ks * 4 + rx) ^ (lrow & 7)) * 8;
                    a[m] = *(const bf16x8*)&As[row * BKG + ch];
                }
#pragma unroll
                for (int n = 0; n < 4; ++n) {
                    const int row = wn * 64 + n * 16 + lrow;
                    const int ch = ((ks * 4 + rx) ^ (lrow & 7)) * 8;
                    bfr[n] = *(const bf16x8*)&Bs[row * BKG + ch];
                }
#pragma unroll
                for (int m = 0; m < 4; ++m)
#pragma unroll
                    for (int n = 0; n < 4; ++n)
                        acc[m][n] = __builtin_amdgcn_mfma_f32_16x16x32_bf16(a[m], bfr[n], acc[m][n], 0, 0, 0);
            }
        }
    }

    float bev[4][4];
#pragma unroll
    for (int n = 0; n < 4; ++n)
#pragma unroll
        for (int e = 0; e < 4; ++e)
            bev[n][e] = be[(size_t)e * H + c0 + n * 16];

#pragma unroll
    for (int m = 0; m < 4; ++m) {
#pragma unroll
        for (int r = 0; r < 4; ++r) {
            const int tl = r0 + m * 16 + r;
            const int slotg = tileM + tl;
            if (slotg < endSlot) {
                const size_t t = (size_t)tlds[tl];
                const float4 wq = *(const float4*)&wlds[tl * 4];
                const float* xr = xin + t * H;
                float* orow = out + t * H;
#pragma unroll
                for (int n = 0; n < 4; ++n) {
                    const int col = c0 + n * 16;
                    const float bias = wq.x * bev[n][0] + wq.y * bev[n][1] +
                                       wq.z * bev[n][2] + wq.w * bev[n][3];
                    orow[col] = xr[col] + acc[m][n][r] + bias;
                }
            }
        }
    }
}

// ---------------------------------------------------------------------------
extern "C" void kernel_launch(void* const* d_in, const int* in_sizes, int n_in,
                              void* d_out, int out_size, void* d_ws, size_t ws_size,
                              hipStream_t stream) {
    (void)in_sizes; (void)n_in; (void)out_size; (void)ws_size;

    const float* x    = (const float*)d_in[0];
    const float* ln_g = (const float*)d_in[1];
    const float* ln_b = (const float*)d_in[2];
    const float* Wr   = (const float*)d_in[3];
    const float* br   = (const float*)d_in[4];
    const float* We   = (const float*)d_in[5];
    const float* be   = (const float*)d_in[6];
    float* out = (float*)d_out;

    uint8_t* ws = (uint8_t*)d_ws;
    const size_t zBytes   = (size_t)MTOK * H * 2;
    const size_t wtBytes  = (size_t)EXPERTS * H * H * 2;
    const size_t wbBytes  = (size_t)MTOK * 4 * 4;
    const size_t zcBytes  = (size_t)FLAG_CAP * H * 2;
    const size_t wfBytes  = (size_t)(FLAG_CAP + 128) * 4 * 4;
    const size_t flgBytes = 8192;
    const size_t zsBytes  = (size_t)NT_MAX * BM * H * 2;   // 55 MB each

    bf16*  z    = (bf16*)ws;                                       ws += zBytes;
    bf16*  WtH  = (bf16*)ws;                                       ws += wtBytes;
    bf16*  WtL  = (bf16*)ws;                                       ws += wtBytes;
    float* wb   = (float*)ws;                                      ws += wbBytes;
    bf16*  zcH  = (bf16*)ws;                                       ws += zcBytes;
    bf16*  zcL  = (bf16*)ws;                                       ws += zcBytes;
    float* wf   = (float*)ws;                                      ws += wfBytes;
    int*   flg  = (int*)ws;                                        ws += flgBytes;
    bf16*  zA   = (bf16*)ws;                                       ws += zsBytes;
    bf16*  zB   = (bf16*)ws;                                       ws += zsBytes;
    int*   bkt  = (int*)ws;                                        ws += (size_t)MTOK * 4;
    int*   slot_of = (int*)ws;                                     ws += (size_t)MTOK * 4;
    int*   tokslot = (int*)ws;                                     ws += (size_t)NT_MAX * BM * 4;
    int*   bcount  = (int*)ws;                                     ws += 256;
    int*   off_g   = (int*)ws;                                     ws += 256;
    int*   tile_bkt = (int*)ws;                                    ws += 1024;
    int*   tile_end = (int*)ws;                                    ws += 1024;
    int*   cursor = bcount + 6;
    // refine partials: 8 slabs x FLAG_CAP x H fp32 = 100.7 MB, spans zA+zB
    // (both regenerated by layer-2 scatter_scale after refine_combine).
    float* partial = (float*)zA;

    const dim3 gemm_grid(H / BN, NT_MAX);

    // ---- layer 1 ----
    we_transpose<1><<<dim3(H / 64, H / 64, EXPERTS), 256, 0, stream>>>(We, WtH, WtL);
    zero12<<<1, 64, 0, stream>>>(bcount);
    ln_router_k<0><<<dim3(MTOK), 256, 0, stream>>>(x, ln_g, ln_b, Wr, br, z, wb, bkt, bcount, flg);
    bucket_scan<<<1, 256, 0, stream>>>(bcount, off_g, tile_bkt, tile_end, tokslot);
    scatter<<<dim3(MTOK / 256), 256, 0, stream>>>(bkt, off_g, cursor, tokslot, slot_of);
    scatter_scale<<<dim3(MTOK), 384, 0, stream>>>(z, wb, bkt, slot_of, zA, zB);
    moe_gemm_b<<<gemm_grid, 256, 0, stream>>>(zA, zB, WtH, tokslot, wb, tile_bkt, tile_end, x, be, out);

    // ---- selective fp32-class refinement for near-tie layer-2 routing ----
    zero_flags<<<1, 64, 0, stream>>>(flg);
    ln_router_k<1><<<dim3(MTOK), 256, 0, stream>>>(out, ln_g + H, ln_b + H,
                                                   Wr + (size_t)H * EXPERTS, br + EXPERTS,
                                                   z, wb, bkt, bcount, flg);
    zfill<<<dim3(FLAG_CAP), 256, 0, stream>>>(x, ln_g, ln_b, flg, wb, zcH, zcL, wf);
    refine_mfma<<<dim3(H / BN, FLAG_CAP / BM, EXPERTS * KSPLIT), 256, 0, stream>>>(
        zcH, zcL, WtH, WtL, wf, flg, partial);
    refine_combine<<<dim3(FLAG_CAP), 256, 0, stream>>>(partial, x, wf, be, flg, out);

    // ---- layer 2 ----
    we_transpose<0><<<dim3(H / 64, H / 64, EXPERTS), 256, 0, stream>>>(
        We + (size_t)EXPERTS * H * H, WtH, WtL);
    zero12<<<1, 64, 0, stream>>>(bcount);
    ln_router_k<0><<<dim3(MTOK), 256, 0, stream>>>(out, ln_g + H, ln_b + H,
                                                   Wr + (size_t)H * EXPERTS, br + EXPERTS,
                                                   z, wb, bkt, bcount, flg);
    bucket_scan<<<1, 256, 0, stream>>>(bcount, off_g, tile_bkt, tile_end, tokslot);
    scatter<<<dim3(MTOK / 256), 256, 0, stream>>>(bkt, off_g, cursor, tokslot, slot_of);
    scatter_scale<<<dim3(MTOK), 384, 0, stream>>>(z, wb, bkt, slot_of, zA, zB);
    moe_gemm_b<<<gemm_grid, 256, 0, stream>>>(zA, zB, WtH, tokslot, wb, tile_bkt, tile_end, out,
                                              be + (size_t)EXPERTS * H, out);
}